// Round 1
// baseline (914.270 us; speedup 1.0000x reference)
//
#include <hip/hip_runtime.h>

#define NH 6
#define HD 32
#define NTOK 49
#define CDIM 192
#define NWIN 1024
#define SCALE 0.17677669529663687f

typedef __bf16 bf16x8 __attribute__((ext_vector_type(8)));
typedef float f32x4 __attribute__((ext_vector_type(4)));
typedef unsigned short u16;
typedef unsigned int u32;

__device__ __forceinline__ u16 f2bf(float x) {
    u32 u = __builtin_bit_cast(u32, x);
    u = (u + 0x7FFFu + ((u >> 16) & 1u)) >> 16;
    return (u16)u;
}

__global__ void build_wb(const float* __restrict__ w, u16* __restrict__ wb) {
    int i = blockIdx.x * 256 + threadIdx.x;
    if (i < CDIM * CDIM) wb[i] = f2bf(w[i]);
}

// One block per window. 256 threads = 4 waves.
// LDS strides: q/k rows 40 u16 (80B=20 banks -> 2-way, free), vT/p rows 72 (144B),
// xb rows 200 (400B). All 16B-aligned for ds_read_b128 fragments.
__global__ __launch_bounds__(256, 3)
void swin_attn(const float* __restrict__ qkv, const int* __restrict__ rpi,
               const float* __restrict__ mask, const float* __restrict__ bias_table,
               const u16* __restrict__ wb, const float* __restrict__ proj_b,
               float* __restrict__ out) {
    __shared__ u16 q_s[64][40];
    __shared__ u16 k_s[64][40];
    __shared__ u16 vT_s[32][72];
    __shared__ u16 p_s[64][72];
    __shared__ u16 xb_s[64][200];

    const int tid = threadIdx.x;
    const int b = blockIdx.x;
    const int wn = b & (NWIN - 1);
    const int wv = tid >> 6;
    const int lane = tid & 63;
    const int lg = lane >> 4;   // 16-lane group 0..3
    const int lc = lane & 15;

    const size_t qkv_base = (size_t)b * (NTOK * 3 * CDIM);
    const float* mrow = mask + (size_t)wn * (NTOK * NTOK);
    const f32x4 fzero = {0.f, 0.f, 0.f, 0.f};

    for (int h = 0; h < NH; ++h) {
        __syncthreads();  // protect LDS from previous iteration's readers
        // ---- stage q (pre-scaled), k, v^T as bf16 ----
        for (int idx = tid; idx < 392; idx += 256) {
            int n = idx >> 3, f = idx & 7;
            const float4 v4 = *reinterpret_cast<const float4*>(qkv + qkv_base + n * 576 + h * 32 + f * 4);
            ushort4 o;
            o.x = f2bf(v4.x * SCALE); o.y = f2bf(v4.y * SCALE);
            o.z = f2bf(v4.z * SCALE); o.w = f2bf(v4.w * SCALE);
            *reinterpret_cast<ushort4*>(&q_s[n][f * 4]) = o;
        }
        for (int idx = tid; idx < 392; idx += 256) {
            int n = idx >> 3, f = idx & 7;
            const float4 v4 = *reinterpret_cast<const float4*>(qkv + qkv_base + n * 576 + 192 + h * 32 + f * 4);
            ushort4 o;
            o.x = f2bf(v4.x); o.y = f2bf(v4.y); o.z = f2bf(v4.z); o.w = f2bf(v4.w);
            *reinterpret_cast<ushort4*>(&k_s[n][f * 4]) = o;
        }
        for (int idx = tid; idx < 392; idx += 256) {
            int n = idx >> 3, f = idx & 7;
            const float4 v4 = *reinterpret_cast<const float4*>(qkv + qkv_base + n * 576 + 384 + h * 32 + f * 4);
            int d = f * 4;
            vT_s[d + 0][n] = f2bf(v4.x);
            vT_s[d + 1][n] = f2bf(v4.y);
            vT_s[d + 2][n] = f2bf(v4.z);
            vT_s[d + 3][n] = f2bf(v4.w);
        }
        // zero vT padding cols 49..64 (avoid 0*NaN in PV)
        for (int idx = tid; idx < 512; idx += 256)
            vT_s[idx >> 4][49 + (idx & 15)] = 0;
        __syncthreads();

        // ---- QK^T: wave wv owns rows 16wv..16wv+15; K=32 in one MFMA ----
        bf16x8 aq = *reinterpret_cast<const bf16x8*>(&q_s[16 * wv + lc][8 * lg]);
        f32x4 acc[4];
#pragma unroll
        for (int t = 0; t < 4; ++t) {
            bf16x8 bk = *reinterpret_cast<const bf16x8*>(&k_s[16 * t + lc][8 * lg]);
            acc[t] = __builtin_amdgcn_mfma_f32_16x16x32_bf16(aq, bk, fzero, 0, 0, 0);
        }

        // ---- softmax: row i = 16wv + 4lg + r; cols j = 16t + lc ----
#pragma unroll
        for (int r = 0; r < 4; ++r) {
            const int i = 16 * wv + 4 * lg + r;
            float vals[4];
#pragma unroll
            for (int t = 0; t < 4; ++t) {
                const int j = 16 * t + lc;
                if (i < NTOK && j < NTOK) {
                    const int ij = i * NTOK + j;
                    float bias = bias_table[rpi[ij] * NH + h];
                    vals[t] = acc[t][r] + bias + mrow[ij];
                } else {
                    vals[t] = -1e30f;
                }
            }
            float m = fmaxf(fmaxf(vals[0], vals[1]), fmaxf(vals[2], vals[3]));
#pragma unroll
            for (int off = 1; off < 16; off <<= 1) m = fmaxf(m, __shfl_xor(m, off, 16));
            float e[4], s = 0.f;
#pragma unroll
            for (int t = 0; t < 4; ++t) { e[t] = __expf(vals[t] - m); s += e[t]; }
#pragma unroll
            for (int off = 1; off < 16; off <<= 1) s += __shfl_xor(s, off, 16);
            const float rs = 1.0f / s;
#pragma unroll
            for (int t = 0; t < 4; ++t) {
                const int j = 16 * t + lc;
                u16 pv = (i < NTOK && j < NTOK) ? f2bf(e[t] * rs) : (u16)0;
                p_s[i][j] = pv;  // wave-private rows: no barrier needed
            }
        }

        // ---- PV: x[64x32] = P[64x64] @ V[64x32] ----
        f32x4 xacc[2] = {fzero, fzero};
#pragma unroll
        for (int ks = 0; ks < 2; ++ks) {
            bf16x8 pa = *reinterpret_cast<const bf16x8*>(&p_s[16 * wv + lc][32 * ks + 8 * lg]);
#pragma unroll
            for (int ct = 0; ct < 2; ++ct) {
                bf16x8 vb = *reinterpret_cast<const bf16x8*>(&vT_s[16 * ct + lc][32 * ks + 8 * lg]);
                xacc[ct] = __builtin_amdgcn_mfma_f32_16x16x32_bf16(pa, vb, xacc[ct], 0, 0, 0);
            }
        }
#pragma unroll
        for (int ct = 0; ct < 2; ++ct)
#pragma unroll
            for (int r = 0; r < 4; ++r)
                xb_s[16 * wv + 4 * lg + r][h * 32 + 16 * ct + lc] = f2bf(xacc[ct][r]);
    }

    __syncthreads();

    // ---- proj: out[49x192] = x[49x192] @ W^T; wave wv owns cols 48wv..48wv+47 ----
    f32x4 pacc[3][4];
#pragma unroll
    for (int ct = 0; ct < 3; ++ct)
#pragma unroll
        for (int rt = 0; rt < 4; ++rt) pacc[ct][rt] = fzero;

#pragma unroll
    for (int ks = 0; ks < 6; ++ks) {
        bf16x8 af[4];
#pragma unroll
        for (int rt = 0; rt < 4; ++rt)
            af[rt] = *reinterpret_cast<const bf16x8*>(&xb_s[16 * rt + lc][32 * ks + 8 * lg]);
#pragma unroll
        for (int ct = 0; ct < 3; ++ct) {
            const int c = 48 * wv + 16 * ct + lc;
            bf16x8 bw = *reinterpret_cast<const bf16x8*>(wb + c * CDIM + 32 * ks + 8 * lg);
#pragma unroll
            for (int rt = 0; rt < 4; ++rt)
                pacc[ct][rt] = __builtin_amdgcn_mfma_f32_16x16x32_bf16(af[rt], bw, pacc[ct][rt], 0, 0, 0);
        }
    }

#pragma unroll
    for (int ct = 0; ct < 3; ++ct) {
        const int c = 48 * wv + 16 * ct + lc;
        const float pb = proj_b[c];
#pragma unroll
        for (int rt = 0; rt < 4; ++rt) {
#pragma unroll
            for (int r = 0; r < 4; ++r) {
                const int i = 16 * rt + 4 * lg + r;
                if (i < NTOK)
                    out[(size_t)b * (NTOK * CDIM) + i * CDIM + c] = pacc[ct][rt][r] + pb;
            }
        }
    }
}

extern "C" void kernel_launch(void* const* d_in, const int* in_sizes, int n_in,
                              void* d_out, int out_size, void* d_ws, size_t ws_size,
                              hipStream_t stream) {
    const float* qkv        = (const float*)d_in[0];
    const int*   rpi        = (const int*)d_in[1];
    const float* mask       = (const float*)d_in[2];
    const float* bias_table = (const float*)d_in[3];
    const float* proj_w     = (const float*)d_in[4];
    const float* proj_b     = (const float*)d_in[5];
    float* out = (float*)d_out;
    u16* wb = (u16*)d_ws;  // bf16 copy of proj_w, 73728 B

    const int nblk = in_sizes[0] / (NTOK * 3 * CDIM);  // 8192 windows

    build_wb<<<(CDIM * CDIM + 255) / 256, 256, 0, stream>>>(proj_w, wb);
    swin_attn<<<nblk, 256, 0, stream>>>(qkv, rpi, mask, bias_table, wb, proj_b, out);
}

// Round 2
// 907.131 us; speedup vs baseline: 1.0079x; 1.0079x over previous
//
#include <hip/hip_runtime.h>

#define NH 6
#define HD 32
#define NTOK 49
#define CDIM 192
#define NWIN 1024
#define SCALE 0.17677669529663687f

typedef __bf16 bf16x8 __attribute__((ext_vector_type(8)));
typedef float f32x4 __attribute__((ext_vector_type(4)));
typedef unsigned short u16;
typedef unsigned int u32;

__device__ __forceinline__ u16 f2bf(float x) {
    u32 u = __builtin_bit_cast(u32, x);
    u = (u + 0x7FFFu + ((u >> 16) & 1u)) >> 16;
    return (u16)u;
}

__global__ void build_wb(const float* __restrict__ w, u16* __restrict__ wb) {
    int i = blockIdx.x * 256 + threadIdx.x;
    if (i < CDIM * CDIM) wb[i] = f2bf(w[i]);
}

// One block per window. 256 threads = 4 waves.
// LDS strides: q/k rows 40 u16 (80B=20 banks -> 2-way, free), vT/p rows 72 (144B),
// xb rows 200 (400B). All 16B-aligned for ds_read_b128 fragments.
__global__ __launch_bounds__(256, 3)
void swin_attn(const float* __restrict__ qkv, const int* __restrict__ rpi,
               const float* __restrict__ mask, const float* __restrict__ bias_table,
               const u16* __restrict__ wb, const float* __restrict__ proj_b,
               float* __restrict__ out) {
    __shared__ u16 q_s[64][40];
    __shared__ u16 k_s[64][40];
    __shared__ u16 vT_s[32][72];
    __shared__ u16 p_s[64][72];
    __shared__ u16 xb_s[64][200];

    const int tid = threadIdx.x;
    const int b = blockIdx.x;
    const int wn = b & (NWIN - 1);
    const int wv = tid >> 6;
    const int lane = tid & 63;
    const int lg = lane >> 4;   // 16-lane group 0..3
    const int lc = lane & 15;

    const size_t qkv_base = (size_t)b * (NTOK * 3 * CDIM);
    const float* mrow = mask + (size_t)wn * (NTOK * NTOK);
    const f32x4 fzero = {0.f, 0.f, 0.f, 0.f};

    for (int h = 0; h < NH; ++h) {
        __syncthreads();  // protect LDS from previous iteration's readers
        // ---- stage q (pre-scaled), k, v^T as bf16 ----
        for (int idx = tid; idx < 392; idx += 256) {
            int n = idx >> 3, f = idx & 7;
            const float4 v4 = *reinterpret_cast<const float4*>(qkv + qkv_base + n * 576 + h * 32 + f * 4);
            ushort4 o;
            o.x = f2bf(v4.x * SCALE); o.y = f2bf(v4.y * SCALE);
            o.z = f2bf(v4.z * SCALE); o.w = f2bf(v4.w * SCALE);
            *reinterpret_cast<ushort4*>(&q_s[n][f * 4]) = o;
        }
        for (int idx = tid; idx < 392; idx += 256) {
            int n = idx >> 3, f = idx & 7;
            const float4 v4 = *reinterpret_cast<const float4*>(qkv + qkv_base + n * 576 + 192 + h * 32 + f * 4);
            ushort4 o;
            o.x = f2bf(v4.x); o.y = f2bf(v4.y); o.z = f2bf(v4.z); o.w = f2bf(v4.w);
            *reinterpret_cast<ushort4*>(&k_s[n][f * 4]) = o;
        }
        for (int idx = tid; idx < 392; idx += 256) {
            int n = idx >> 3, f = idx & 7;
            const float4 v4 = *reinterpret_cast<const float4*>(qkv + qkv_base + n * 576 + 384 + h * 32 + f * 4);
            int d = f * 4;
            vT_s[d + 0][n] = f2bf(v4.x);
            vT_s[d + 1][n] = f2bf(v4.y);
            vT_s[d + 2][n] = f2bf(v4.z);
            vT_s[d + 3][n] = f2bf(v4.w);
        }
        // zero vT padding cols 49..64 (avoid 0*NaN in PV)
        for (int idx = tid; idx < 512; idx += 256)
            vT_s[idx >> 4][49 + (idx & 15)] = 0;
        __syncthreads();

        // ---- QK^T: wave wv owns rows 16wv..16wv+15; K=32 in one MFMA ----
        bf16x8 aq = *reinterpret_cast<const bf16x8*>(&q_s[16 * wv + lc][8 * lg]);
        f32x4 acc[4];
#pragma unroll
        for (int t = 0; t < 4; ++t) {
            bf16x8 bk = *reinterpret_cast<const bf16x8*>(&k_s[16 * t + lc][8 * lg]);
            acc[t] = __builtin_amdgcn_mfma_f32_16x16x32_bf16(aq, bk, fzero, 0, 0, 0);
        }

        // ---- softmax: row i = 16wv + 4lg + r; cols j = 16t + lc ----
#pragma unroll
        for (int r = 0; r < 4; ++r) {
            const int i = 16 * wv + 4 * lg + r;
            float vals[4];
#pragma unroll
            for (int t = 0; t < 4; ++t) {
                const int j = 16 * t + lc;
                if (i < NTOK && j < NTOK) {
                    const int ij = i * NTOK + j;
                    float bias = bias_table[rpi[ij] * NH + h];
                    vals[t] = acc[t][r] + bias + mrow[ij];
                } else {
                    vals[t] = -1e30f;
                }
            }
            float m = fmaxf(fmaxf(vals[0], vals[1]), fmaxf(vals[2], vals[3]));
#pragma unroll
            for (int off = 1; off < 16; off <<= 1) m = fmaxf(m, __shfl_xor(m, off, 16));
            float e[4], s = 0.f;
#pragma unroll
            for (int t = 0; t < 4; ++t) { e[t] = __expf(vals[t] - m); s += e[t]; }
#pragma unroll
            for (int off = 1; off < 16; off <<= 1) s += __shfl_xor(s, off, 16);
            const float rs = 1.0f / s;
#pragma unroll
            for (int t = 0; t < 4; ++t) {
                const int j = 16 * t + lc;
                u16 pv = (i < NTOK && j < NTOK) ? f2bf(e[t] * rs) : (u16)0;
                p_s[i][j] = pv;  // wave-private rows: no barrier needed
            }
        }

        // ---- PV: x[64x32] = P[64x64] @ V[64x32] ----
        f32x4 xacc[2] = {fzero, fzero};
#pragma unroll
        for (int ks = 0; ks < 2; ++ks) {
            bf16x8 pa = *reinterpret_cast<const bf16x8*>(&p_s[16 * wv + lc][32 * ks + 8 * lg]);
#pragma unroll
            for (int ct = 0; ct < 2; ++ct) {
                bf16x8 vb = *reinterpret_cast<const bf16x8*>(&vT_s[16 * ct + lc][32 * ks + 8 * lg]);
                xacc[ct] = __builtin_amdgcn_mfma_f32_16x16x32_bf16(pa, vb, xacc[ct], 0, 0, 0);
            }
        }
#pragma unroll
        for (int ct = 0; ct < 2; ++ct)
#pragma unroll
            for (int r = 0; r < 4; ++r)
                xb_s[16 * wv + 4 * lg + r][h * 32 + 16 * ct + lc] = f2bf(xacc[ct][r]);
    }

    __syncthreads();

    // ---- proj: out[49x192] = x[49x192] @ W^T; wave wv owns cols 48wv..48wv+47 ----
    f32x4 pacc[3][4];
#pragma unroll
    for (int ct = 0; ct < 3; ++ct)
#pragma unroll
        for (int rt = 0; rt < 4; ++rt) pacc[ct][rt] = fzero;

#pragma unroll
    for (int ks = 0; ks < 6; ++ks) {
        bf16x8 af[4];
#pragma unroll
        for (int rt = 0; rt < 4; ++rt)
            af[rt] = *reinterpret_cast<const bf16x8*>(&xb_s[16 * rt + lc][32 * ks + 8 * lg]);
#pragma unroll
        for (int ct = 0; ct < 3; ++ct) {
            const int c = 48 * wv + 16 * ct + lc;
            bf16x8 bw = *reinterpret_cast<const bf16x8*>(wb + c * CDIM + 32 * ks + 8 * lg);
#pragma unroll
            for (int rt = 0; rt < 4; ++rt)
                pacc[ct][rt] = __builtin_amdgcn_mfma_f32_16x16x32_bf16(af[rt], bw, pacc[ct][rt], 0, 0, 0);
        }
    }

#pragma unroll
    for (int ct = 0; ct < 3; ++ct) {
        const int c = 48 * wv + 16 * ct + lc;
        const float pb = proj_b[c];
#pragma unroll
        for (int rt = 0; rt < 4; ++rt) {
#pragma unroll
            for (int r = 0; r < 4; ++r) {
                const int i = 16 * rt + 4 * lg + r;
                if (i < NTOK)
                    out[(size_t)b * (NTOK * CDIM) + i * CDIM + c] = pacc[ct][rt][r] + pb;
            }
        }
    }
}

extern "C" void kernel_launch(void* const* d_in, const int* in_sizes, int n_in,
                              void* d_out, int out_size, void* d_ws, size_t ws_size,
                              hipStream_t stream) {
    const float* qkv        = (const float*)d_in[0];
    const int*   rpi        = (const int*)d_in[1];
    const float* mask       = (const float*)d_in[2];
    const float* bias_table = (const float*)d_in[3];
    const float* proj_w     = (const float*)d_in[4];
    const float* proj_b     = (const float*)d_in[5];
    float* out = (float*)d_out;
    u16* wb = (u16*)d_ws;  // bf16 copy of proj_w, 73728 B

    const int nblk = in_sizes[0] / (NTOK * 3 * CDIM);  // 8192 windows

    build_wb<<<(CDIM * CDIM + 255) / 256, 256, 0, stream>>>(proj_w, wb);
    swin_attn<<<nblk, 256, 0, stream>>>(qkv, rpi, mask, bias_table, wb, proj_b, out);
}

// Round 3
// 549.697 us; speedup vs baseline: 1.6632x; 1.6502x over previous
//
#include <hip/hip_runtime.h>

#define NH 6
#define NTOK 49
#define CDIM 192
#define NWIN 1024
#define SCALE 0.17677669529663687f

typedef __bf16 bf16x8 __attribute__((ext_vector_type(8)));
typedef float f32x4 __attribute__((ext_vector_type(4)));
typedef unsigned short u16;
typedef u16 u16x8 __attribute__((ext_vector_type(8)));
typedef unsigned int u32;

__device__ __forceinline__ u16 f2bf(float x) {
    u32 u = __builtin_bit_cast(u32, x);
    u = (u + 0x7FFFu + ((u >> 16) & 1u)) >> 16;
    return (u16)u;
}

__global__ void build_wb(const float* __restrict__ w, u16* __restrict__ wb) {
    int i = blockIdx.x * 256 + threadIdx.x;
    if (i < CDIM * CDIM) wb[i] = f2bf(w[i]);
}

// One block per window, 256 threads = 4 waves.
// LDS = 39424 B -> 4 blocks/CU (vs 49664 -> 3). Q/K MFMA fragments load
// directly global->reg (contiguous 32B/lane slices, no staging, no transpose).
// Only V (needs transpose) and P/x go through LDS.
__global__ __launch_bounds__(256, 4)
void swin_attn(const float* __restrict__ qkv, const int* __restrict__ rpi,
               const float* __restrict__ mask, const float* __restrict__ bias_table,
               const u16* __restrict__ wb, const float* __restrict__ proj_b,
               float* __restrict__ out) {
    __shared__ u16 vT_s[32][72];   // V^T: [d][n], row 144B (2-way alias, free)
    __shared__ u16 p_s[64][72];    // P, wave-private row stripes
    __shared__ u16 xb_s[64][200];  // attention output x, bf16

    const int tid = threadIdx.x;
    const int b = blockIdx.x;
    const int wn = b & (NWIN - 1);
    const int wv = tid >> 6;
    const int lane = tid & 63;
    const int lg = lane >> 4;
    const int lc = lane & 15;

    const size_t qkv_base = (size_t)b * (NTOK * 3 * CDIM);
    const float* mrow = mask + (size_t)wn * (NTOK * NTOK);
    const f32x4 fzero = {0.f, 0.f, 0.f, 0.f};

    // ---- hoist head-invariant mask + rpi (16 each, kept in regs) ----
    float madd[4][4];
    int bidx[4][4];
#pragma unroll
    for (int r = 0; r < 4; ++r) {
        const int i = 16 * wv + 4 * lg + r;
#pragma unroll
        for (int t = 0; t < 4; ++t) {
            const int j = 16 * t + lc;
            const bool valid = (i < NTOK) && (j < NTOK);
            const int ij = valid ? i * NTOK + j : 0;
            madd[r][t] = valid ? mrow[ij] : -1e30f;
            bidx[r][t] = rpi[ij] * NH;
        }
    }

    // ---- zero vT pad cols 49..63 once (head loop only rewrites cols 0..48) ----
    for (int idx = tid; idx < 512; idx += 256) {
        const int row = idx >> 4, m = idx & 15;
        if (m) vT_s[row][48 + m] = 0;
    }

    // ---- prefetch V for h=0 (2 float4 slots/thread; slot0 always valid) ----
    float4 vp0 = {0, 0, 0, 0}, vp1 = {0, 0, 0, 0};
    {
        const int n = tid >> 3, f = tid & 7;
        vp0 = *reinterpret_cast<const float4*>(qkv + qkv_base + n * 576 + 2 * CDIM + f * 4);
    }
    if (tid + 256 < 392) {
        const int idx = tid + 256, n = idx >> 3, f = idx & 7;
        vp1 = *reinterpret_cast<const float4*>(qkv + qkv_base + n * 576 + 2 * CDIM + f * 4);
    }

    for (int h = 0; h < NH; ++h) {
        __syncthreads();  // all waves done reading vT of previous head
        // ---- write prefetched V (transposed) to LDS ----
        {
            const int n = tid >> 3, d = (tid & 7) * 4;
            vT_s[d + 0][n] = f2bf(vp0.x);
            vT_s[d + 1][n] = f2bf(vp0.y);
            vT_s[d + 2][n] = f2bf(vp0.z);
            vT_s[d + 3][n] = f2bf(vp0.w);
        }
        if (tid + 256 < 392) {
            const int idx = tid + 256, n = idx >> 3, d = (idx & 7) * 4;
            vT_s[d + 0][n] = f2bf(vp1.x);
            vT_s[d + 1][n] = f2bf(vp1.y);
            vT_s[d + 2][n] = f2bf(vp1.z);
            vT_s[d + 3][n] = f2bf(vp1.w);
        }
        __syncthreads();  // vT[h] ready

        // ---- prefetch V for h+1 (latency hides under this head's compute) ----
        if (h + 1 < NH) {
            {
                const int n = tid >> 3, f = tid & 7;
                vp0 = *reinterpret_cast<const float4*>(
                    qkv + qkv_base + n * 576 + 2 * CDIM + (h + 1) * 32 + f * 4);
            }
            if (tid + 256 < 392) {
                const int idx = tid + 256, n = idx >> 3, f = idx & 7;
                vp1 = *reinterpret_cast<const float4*>(
                    qkv + qkv_base + n * 576 + 2 * CDIM + (h + 1) * 32 + f * 4);
            }
        }

        // ---- Q fragment: direct global->reg (row clamped: pad rows masked later) ----
        const int qrow = (16 * wv + lc < NTOK) ? 16 * wv + lc : NTOK - 1;
        const float* qp = qkv + qkv_base + (size_t)qrow * 576 + h * 32 + 8 * lg;
        const float4 qa = *reinterpret_cast<const float4*>(qp);
        const float4 qb = *reinterpret_cast<const float4*>(qp + 4);
        u16x8 qv;
        qv[0] = f2bf(qa.x * SCALE); qv[1] = f2bf(qa.y * SCALE);
        qv[2] = f2bf(qa.z * SCALE); qv[3] = f2bf(qa.w * SCALE);
        qv[4] = f2bf(qb.x * SCALE); qv[5] = f2bf(qb.y * SCALE);
        qv[6] = f2bf(qb.z * SCALE); qv[7] = f2bf(qb.w * SCALE);
        const bf16x8 aq = __builtin_bit_cast(bf16x8, qv);

        // ---- K fragments direct global->reg + QK^T ----
        f32x4 acc[4];
#pragma unroll
        for (int t = 0; t < 4; ++t) {
            const int krow = (16 * t + lc < NTOK) ? 16 * t + lc : NTOK - 1;
            const float* kp = qkv + qkv_base + (size_t)krow * 576 + CDIM + h * 32 + 8 * lg;
            const float4 ka = *reinterpret_cast<const float4*>(kp);
            const float4 kb = *reinterpret_cast<const float4*>(kp + 4);
            u16x8 kv;
            kv[0] = f2bf(ka.x); kv[1] = f2bf(ka.y); kv[2] = f2bf(ka.z); kv[3] = f2bf(ka.w);
            kv[4] = f2bf(kb.x); kv[5] = f2bf(kb.y); kv[6] = f2bf(kb.z); kv[7] = f2bf(kb.w);
            acc[t] = __builtin_amdgcn_mfma_f32_16x16x32_bf16(
                aq, __builtin_bit_cast(bf16x8, kv), fzero, 0, 0, 0);
        }

        // ---- softmax: row i = 16wv+4lg+r, cols j = 16t+lc ----
#pragma unroll
        for (int r = 0; r < 4; ++r) {
            const int i = 16 * wv + 4 * lg + r;
            float vals[4];
#pragma unroll
            for (int t = 0; t < 4; ++t)
                vals[t] = acc[t][r] + bias_table[bidx[r][t] + h] + madd[r][t];
            float m = fmaxf(fmaxf(vals[0], vals[1]), fmaxf(vals[2], vals[3]));
#pragma unroll
            for (int off = 1; off < 16; off <<= 1) m = fmaxf(m, __shfl_xor(m, off, 16));
            float e[4], s = 0.f;
#pragma unroll
            for (int t = 0; t < 4; ++t) { e[t] = __expf(vals[t] - m); s += e[t]; }
#pragma unroll
            for (int off = 1; off < 16; off <<= 1) s += __shfl_xor(s, off, 16);
            const float rs = 1.0f / s;
#pragma unroll
            for (int t = 0; t < 4; ++t)
                p_s[i][16 * t + lc] = f2bf(e[t] * rs);  // wave-private rows
        }

        // ---- PV: x[64x32] = P[64x64] @ V[64x32] ----
        f32x4 xacc[2] = {fzero, fzero};
#pragma unroll
        for (int ks = 0; ks < 2; ++ks) {
            const bf16x8 pa = *reinterpret_cast<const bf16x8*>(&p_s[16 * wv + lc][32 * ks + 8 * lg]);
#pragma unroll
            for (int ct = 0; ct < 2; ++ct) {
                const bf16x8 vb = *reinterpret_cast<const bf16x8*>(&vT_s[16 * ct + lc][32 * ks + 8 * lg]);
                xacc[ct] = __builtin_amdgcn_mfma_f32_16x16x32_bf16(pa, vb, xacc[ct], 0, 0, 0);
            }
        }
#pragma unroll
        for (int ct = 0; ct < 2; ++ct)
#pragma unroll
            for (int r = 0; r < 4; ++r)
                xb_s[16 * wv + 4 * lg + r][h * 32 + 16 * ct + lc] = f2bf(xacc[ct][r]);
    }

    __syncthreads();

    // ---- proj: out[49x192] = x @ W^T; wave wv owns cols 48wv..48wv+47 ----
    f32x4 pacc[3][4];
#pragma unroll
    for (int ct = 0; ct < 3; ++ct)
#pragma unroll
        for (int rt = 0; rt < 4; ++rt) pacc[ct][rt] = fzero;

#pragma unroll
    for (int ks = 0; ks < 6; ++ks) {
        bf16x8 af[4];
#pragma unroll
        for (int rt = 0; rt < 4; ++rt)
            af[rt] = *reinterpret_cast<const bf16x8*>(&xb_s[16 * rt + lc][32 * ks + 8 * lg]);
#pragma unroll
        for (int ct = 0; ct < 3; ++ct) {
            const int c = 48 * wv + 16 * ct + lc;
            const bf16x8 bw = *reinterpret_cast<const bf16x8*>(wb + c * CDIM + 32 * ks + 8 * lg);
#pragma unroll
            for (int rt = 0; rt < 4; ++rt)
                pacc[ct][rt] = __builtin_amdgcn_mfma_f32_16x16x32_bf16(af[rt], bw, pacc[ct][rt], 0, 0, 0);
        }
    }

#pragma unroll
    for (int ct = 0; ct < 3; ++ct) {
        const int c = 48 * wv + 16 * ct + lc;
        const float pb = proj_b[c];
#pragma unroll
        for (int rt = 0; rt < 4; ++rt) {
#pragma unroll
            for (int r = 0; r < 4; ++r) {
                const int i = 16 * rt + 4 * lg + r;
                if (i < NTOK)
                    out[(size_t)b * (NTOK * CDIM) + i * CDIM + c] = pacc[ct][rt][r] + pb;
            }
        }
    }
}

extern "C" void kernel_launch(void* const* d_in, const int* in_sizes, int n_in,
                              void* d_out, int out_size, void* d_ws, size_t ws_size,
                              hipStream_t stream) {
    const float* qkv        = (const float*)d_in[0];
    const int*   rpi        = (const int*)d_in[1];
    const float* mask       = (const float*)d_in[2];
    const float* bias_table = (const float*)d_in[3];
    const float* proj_w     = (const float*)d_in[4];
    const float* proj_b     = (const float*)d_in[5];
    float* out = (float*)d_out;
    u16* wb = (u16*)d_ws;  // bf16 copy of proj_w (73728 B)

    const int nblk = in_sizes[0] / (NTOK * 3 * CDIM);  // 8192 windows

    build_wb<<<(CDIM * CDIM + 255) / 256, 256, 0, stream>>>(proj_w, wb);
    swin_attn<<<nblk, 256, 0, stream>>>(qkv, rpi, mask, bias_table, wb, proj_b, out);
}